// Round 1
// baseline (297.986 us; speedup 1.0000x reference)
//
#include <hip/hip_runtime.h>

#define HW 96
#define NPIX 9216
#define CDIM 64
#define NH 2
#define HD 32
#define KK 49
#define QN 192
#define SCALE 0.17677669529663687f

// ---------------------------------------------------------------------------
// Shared device helper: one 96-wide half of the 192x64 qkv GEMM for a
// 64-pixel tile. xsrc = LDS [c*65 + pl] (64x64 tile, padded stride 65).
// ws = LDS scratch [96*65]. Internal barriers; must be called by all 256
// threads uniformly.
// ---------------------------------------------------------------------------
__device__ __forceinline__ void qkv_half(const float* __restrict__ xsrc,
                                         float* __restrict__ ws,
                                         const float* __restrict__ qw,
                                         const float* __restrict__ qb,
                                         float* __restrict__ outp,
                                         int p0, int jbase, int t)
{
    // load 96x64 weight half into LDS (padded rows)
    #pragma unroll
    for (int it = 0; it < 24; ++it) {
        int l = it * 256 + t;                 // 0..6143
        ws[(l >> 6) * 65 + (l & 63)] = qw[jbase * 64 + l];
    }
    __syncthreads();
    const int pg = t & 15;                    // 4 pixels: pg*4 .. pg*4+3
    const int jg = t >> 4;                    // 6 outputs: jg*6 .. jg*6+5
    float acc[4][6];
    #pragma unroll
    for (int jj = 0; jj < 6; ++jj) {
        float bv = qb[jbase + jg * 6 + jj];
        #pragma unroll
        for (int ii = 0; ii < 4; ++ii) acc[ii][jj] = bv;
    }
    #pragma unroll 4
    for (int c = 0; c < 64; ++c) {
        float xv[4], wv[6];
        #pragma unroll
        for (int ii = 0; ii < 4; ++ii) xv[ii] = xsrc[c * 65 + pg * 4 + ii];
        #pragma unroll
        for (int jj = 0; jj < 6; ++jj) wv[jj] = ws[(jg * 6 + jj) * 65 + c];
        #pragma unroll
        for (int ii = 0; ii < 4; ++ii)
            #pragma unroll
            for (int jj = 0; jj < 6; ++jj)
                acc[ii][jj] = fmaf(xv[ii], wv[jj], acc[ii][jj]);
    }
    #pragma unroll
    for (int ii = 0; ii < 4; ++ii)
        #pragma unroll
        for (int jj = 0; jj < 6; ++jj)
            outp[(p0 + pg * 4 + ii) * QN + jbase + jg * 6 + jj] = acc[ii][jj];
    __syncthreads();   // before caller reuses ws
}

// ---------------------------------------------------------------------------
// Stage-0 QKV: reads x in native (C,H,W) layout (coalesced: lanes vary pixel),
// writes qkv[p][192].
// ---------------------------------------------------------------------------
__global__ __launch_bounds__(256) void k_qkv0(const float* __restrict__ x,
                                              const float* __restrict__ w,
                                              const float* __restrict__ b,
                                              float* __restrict__ qkv)
{
    __shared__ float xs[64 * 65];
    __shared__ float ws[96 * 65];
    const int t = threadIdx.x;
    const int p0 = blockIdx.x * 64;
    #pragma unroll
    for (int it = 0; it < 16; ++it) {
        int c = it * 4 + (t >> 6);
        xs[c * 65 + (t & 63)] = x[c * NPIX + p0 + (t & 63)];
    }
    qkv_half(xs, ws, w, b, qkv, p0, 0, t);
    qkv_half(xs, ws, w, b, qkv, p0, 96, t);
}

// ---------------------------------------------------------------------------
// Attention: one thread per (pixel, head). 64-thread blocks covering a 4x8
// pixel tile x 2 heads. All neighbor arrays fully unrolled (static register
// indexing). Writes normalized attention (for next stage) and attn-out.
// ---------------------------------------------------------------------------
__global__ __launch_bounds__(64) void k_attn(const float* __restrict__ qkv,
                                             const float* __restrict__ rpb,
                                             const float* __restrict__ prev,
                                             float* __restrict__ cur,
                                             float* __restrict__ aout,
                                             int has_prev)
{
    const int t = threadIdx.x;
    const int bi = blockIdx.x / 12;           // 24 row tiles of 4
    const int bj = blockIdx.x % 12;           // 12 col tiles of 8
    const int i = bi * 4 + ((t >> 3) & 3);
    const int j = bj * 8 + (t & 7);
    const int h = t >> 5;
    const int p = i * HW + j;
    int si = i - 3; si = si < 0 ? 0 : (si > 89 ? 89 : si);
    int sj = j - 3; sj = sj < 0 ? 0 : (sj > 89 ? 89 : sj);

    float4 q[8];
    {
        const float4* qp = (const float4*)(qkv + p * QN + h * HD);
        #pragma unroll
        for (int d = 0; d < 8; ++d) {
            float4 v = qp[d];
            v.x *= SCALE; v.y *= SCALE; v.z *= SCALE; v.w *= SCALE;
            q[d] = v;
        }
    }
    float lg[KK];
    #pragma unroll
    for (int a = 0; a < 7; ++a) {
        #pragma unroll
        for (int bb = 0; bb < 7; ++bb) {
            const float4* kp = (const float4*)(qkv + ((si + a) * HW + sj + bb) * QN + 64 + h * HD);
            float s = 0.f;
            #pragma unroll
            for (int d = 0; d < 8; ++d) {
                float4 kv = kp[d];
                s = fmaf(q[d].x, kv.x, s);
                s = fmaf(q[d].y, kv.y, s);
                s = fmaf(q[d].z, kv.z, s);
                s = fmaf(q[d].w, kv.w, s);
            }
            lg[a * 7 + bb] = s;
        }
    }
    const float* rp = rpb + h * 169;
    const int rh0 = si - i + 6, rw0 = sj - j + 6;
    float mx = -1e30f;
    #pragma unroll
    for (int a = 0; a < 7; ++a) {
        #pragma unroll
        for (int bb = 0; bb < 7; ++bb) {
            float l = lg[a * 7 + bb] + rp[(rh0 + a) * 13 + rw0 + bb];
            if (has_prev) l += prev[(p * 2 + h) * KK + a * 7 + bb];
            lg[a * 7 + bb] = l;
            mx = fmaxf(mx, l);
        }
    }
    float sum = 0.f;
    #pragma unroll
    for (int n = 0; n < KK; ++n) {
        float e = expf(lg[n] - mx);
        lg[n] = e;
        sum += e;
    }
    const float inv = 1.f / sum;
    #pragma unroll
    for (int n = 0; n < KK; ++n) {
        lg[n] *= inv;
        cur[(p * 2 + h) * KK + n] = lg[n];
    }
    float4 acc[8];
    #pragma unroll
    for (int d = 0; d < 8; ++d) acc[d] = make_float4(0.f, 0.f, 0.f, 0.f);
    #pragma unroll
    for (int a = 0; a < 7; ++a) {
        #pragma unroll
        for (int bb = 0; bb < 7; ++bb) {
            const float wgt = lg[a * 7 + bb];
            const float4* vp = (const float4*)(qkv + ((si + a) * HW + sj + bb) * QN + 128 + h * HD);
            #pragma unroll
            for (int d = 0; d < 8; ++d) {
                float4 vv = vp[d];
                acc[d].x = fmaf(wgt, vv.x, acc[d].x);
                acc[d].y = fmaf(wgt, vv.y, acc[d].y);
                acc[d].z = fmaf(wgt, vv.z, acc[d].z);
                acc[d].w = fmaf(wgt, vv.w, acc[d].w);
            }
        }
    }
    float4* op = (float4*)(aout + p * CDIM + h * HD);
    #pragma unroll
    for (int d = 0; d < 8; ++d) op[d] = acc[d];
}

// ---------------------------------------------------------------------------
// Proj (+ next-stage QKV, fused). LAST=1: only proj, writes d_out transposed.
// ---------------------------------------------------------------------------
template <int LAST>
__global__ __launch_bounds__(256) void k_proj(const float* __restrict__ ain,
                                              const float* __restrict__ pw,
                                              const float* __restrict__ pb,
                                              const float* __restrict__ qw,
                                              const float* __restrict__ qb,
                                              float* __restrict__ outp)
{
    __shared__ float xs[64 * 65];
    __shared__ float ws[96 * 65];
    const int t = threadIdx.x;
    const int p0 = blockIdx.x * 64;
    // load attn-out tile, transposed into [c][pl] (coalesced global reads)
    #pragma unroll
    for (int it = 0; it < 16; ++it) {
        int pl = it * 4 + (t >> 6);
        int c = t & 63;
        xs[c * 65 + pl] = ain[(p0 + pl) * CDIM + c];
    }
    // load proj weights
    #pragma unroll
    for (int it = 0; it < 16; ++it) {
        int l = it * 256 + t;                 // 0..4095
        ws[(l >> 6) * 65 + (l & 63)] = pw[l];
    }
    __syncthreads();
    const int pg = t & 15, jg = t >> 4;
    float pacc[4][4];
    #pragma unroll
    for (int jj = 0; jj < 4; ++jj) {
        float bv = pb[jg * 4 + jj];
        #pragma unroll
        for (int ii = 0; ii < 4; ++ii) pacc[ii][jj] = bv;
    }
    #pragma unroll 4
    for (int c = 0; c < 64; ++c) {
        float xv[4], wv[4];
        #pragma unroll
        for (int ii = 0; ii < 4; ++ii) xv[ii] = xs[c * 65 + pg * 4 + ii];
        #pragma unroll
        for (int jj = 0; jj < 4; ++jj) wv[jj] = ws[(jg * 4 + jj) * 65 + c];
        #pragma unroll
        for (int ii = 0; ii < 4; ++ii)
            #pragma unroll
            for (int jj = 0; jj < 4; ++jj)
                pacc[ii][jj] = fmaf(xv[ii], wv[jj], pacc[ii][jj]);
    }
    __syncthreads();   // all proj reads of xs/ws done
    // write xh back into xs (overwrite input tile)
    #pragma unroll
    for (int ii = 0; ii < 4; ++ii)
        #pragma unroll
        for (int jj = 0; jj < 4; ++jj)
            xs[(jg * 4 + jj) * 65 + pg * 4 + ii] = pacc[ii][jj];
    if (LAST) {
        __syncthreads();
        // final output: out[c][p] (coalesced, lanes vary pixel)
        #pragma unroll
        for (int it = 0; it < 16; ++it) {
            int c = it * 4 + (t >> 6);
            outp[c * NPIX + p0 + (t & 63)] = xs[c * 65 + (t & 63)];
        }
        return;
    }
    qkv_half(xs, ws, qw, qb, outp, p0, 0, t);
    qkv_half(xs, ws, qw, qb, outp, p0, 96, t);
}

extern "C" void kernel_launch(void* const* d_in, const int* in_sizes, int n_in,
                              void* d_out, int out_size, void* d_ws, size_t ws_size,
                              hipStream_t stream)
{
    const float* x   = (const float*)d_in[0];
    const float* qw  = (const float*)d_in[1];   // (3,192,64)
    const float* qb  = (const float*)d_in[2];   // (3,192)
    const float* pw  = (const float*)d_in[3];   // (3,64,64)
    const float* pb  = (const float*)d_in[4];   // (3,64)
    const float* rpb = (const float*)d_in[5];   // (3,2,13,13)
    float* out = (float*)d_out;
    float* ws  = (float*)d_ws;

    float* qkv  = ws;                       // 9216*192 = 1,769,472 floats
    float* attA = qkv + 1769472;            // 9216*2*49 = 903,168
    float* attB = attA + 903168;            // 903,168
    float* aout = attB + 903168;            // 9216*64  = 589,824

    // stage 0
    k_qkv0<<<144, 256, 0, stream>>>(x, qw, qb, qkv);
    k_attn<<<288, 64, 0, stream>>>(qkv, rpb, nullptr, attA, aout, 0);
    k_proj<0><<<144, 256, 0, stream>>>(aout, pw, pb, qw + 12288, qb + 192, qkv);
    // stage 1
    k_attn<<<288, 64, 0, stream>>>(qkv, rpb + 338, attA, attB, aout, 1);
    k_proj<0><<<144, 256, 0, stream>>>(aout, pw + 4096, pb + 64, qw + 24576, qb + 384, qkv);
    // stage 2
    k_attn<<<288, 64, 0, stream>>>(qkv, rpb + 676, attB, attA, aout, 1);
    k_proj<1><<<144, 256, 0, stream>>>(aout, pw + 8192, pb + 128, nullptr, nullptr, out);
}

// Round 2
// 188.042 us; speedup vs baseline: 1.5847x; 1.5847x over previous
//
#include <hip/hip_runtime.h>

#define HW 96
#define NPIX 9216
#define QN 192
#define ASTRIDE 52
#define SCALE 0.17677669529663687f

// tile pixel -> global pixel (288 blocks = 24 x 12 tiles of 4x8 pixels)
__device__ __forceinline__ int pmap(int bi, int bj, int px) {
    return (bi * 4 + (px >> 3)) * HW + bj * 8 + (px & 7);
}
// XOR-swizzled LDS word address: linear [rows][64], 4-word column block XOR'd
// by a row-derived selector so strided row-groups spread across all 32 banks.
__device__ __forceinline__ int swz(int row, int col, int sel) {
    return row * 64 + (((col & 60) ^ ((sel & 7) << 2)) | (col & 3));
}

// GEMM: xs[32px][64c] (sel=px>>2) x ws[192j][64c]^T (sel=j>>3) -> qkv[p][192]
// t<192: pxg=t&7 owns 4 px, jo=t>>3 owns 8 j.
__device__ __forceinline__ void qkv_gemm(const float* __restrict__ xs,
                                         const float* __restrict__ ws,
                                         const float* __restrict__ qb,
                                         float* __restrict__ qkv,
                                         int bi, int bj, int t)
{
    if (t >= 192) return;
    const int pxg = t & 7, jo = t >> 3;
    const int j0 = jo * 8;
    float acc[4][8];
    #pragma unroll
    for (int jj = 0; jj < 8; ++jj) {
        float bv = qb[j0 + jj];
        #pragma unroll
        for (int ii = 0; ii < 4; ++ii) acc[ii][jj] = bv;
    }
    #pragma unroll
    for (int cc = 0; cc < 16; ++cc) {
        float4 xv[4], wv[8];
        #pragma unroll
        for (int ii = 0; ii < 4; ++ii)
            xv[ii] = *(const float4*)&xs[swz(pxg * 4 + ii, cc * 4, pxg)];
        #pragma unroll
        for (int jj = 0; jj < 8; ++jj)
            wv[jj] = *(const float4*)&ws[swz(j0 + jj, cc * 4, jo)];
        #pragma unroll
        for (int ii = 0; ii < 4; ++ii)
            #pragma unroll
            for (int jj = 0; jj < 8; ++jj) {
                acc[ii][jj] = fmaf(xv[ii].x, wv[jj].x, acc[ii][jj]);
                acc[ii][jj] = fmaf(xv[ii].y, wv[jj].y, acc[ii][jj]);
                acc[ii][jj] = fmaf(xv[ii].z, wv[jj].z, acc[ii][jj]);
                acc[ii][jj] = fmaf(xv[ii].w, wv[jj].w, acc[ii][jj]);
            }
    }
    #pragma unroll
    for (int ii = 0; ii < 4; ++ii) {
        int p = pmap(bi, bj, pxg * 4 + ii);
        *(float4*)&qkv[p * QN + j0]     = make_float4(acc[ii][0], acc[ii][1], acc[ii][2], acc[ii][3]);
        *(float4*)&qkv[p * QN + j0 + 4] = make_float4(acc[ii][4], acc[ii][5], acc[ii][6], acc[ii][7]);
    }
}

// SRC=0: read x in (C,H,W); SRC=1: read xh in (p,64)
template <int SRC>
__global__ __launch_bounds__(256) void k_qkv(const float* __restrict__ src,
                                             const float* __restrict__ qw,
                                             const float* __restrict__ qb,
                                             float* __restrict__ qkv)
{
    __shared__ float xs[32 * 64];
    __shared__ float ws[192 * 64];
    const int t = threadIdx.x;
    const int bi = blockIdx.x / 12, bj = blockIdx.x % 12;
    if (SRC == 0) {
        #pragma unroll
        for (int it = 0; it < 8; ++it) {
            int l = it * 256 + t;
            int c = l >> 5, px = l & 31;
            xs[swz(px, c, px >> 2)] = src[c * NPIX + pmap(bi, bj, px)];
        }
    } else {
        #pragma unroll
        for (int it = 0; it < 8; ++it) {
            int px = it * 4 + (t >> 6), c = t & 63;
            xs[swz(px, c, px >> 2)] = src[pmap(bi, bj, px) * 64 + c];
        }
    }
    #pragma unroll
    for (int it = 0; it < 12; ++it) {
        int l = it * 256 + t;
        int j = l >> 4, cs = (l & 15) * 4;
        *(float4*)&ws[swz(j, cs, j >> 3)] = *(const float4*)&qw[j * 64 + cs];
    }
    __syncthreads();
    qkv_gemm(xs, ws, qb, qkv, bi, bj, t);
}

// Fused neighborhood attention + proj. 256 threads: attn as 64 quads
// (4 lanes x 8 dims per (pixel,head)), proj as 8 pxg x 32 jo.
template <int HASPREV, int LAST>
__global__ __launch_bounds__(256) void k_stage(const float* __restrict__ qkv,
                                               const float* __restrict__ rpb,
                                               const float* __restrict__ prev,
                                               float* __restrict__ cur,
                                               const float* __restrict__ pw,
                                               const float* __restrict__ pb,
                                               float* __restrict__ xh,
                                               float* __restrict__ outp)
{
    __shared__ float xs[32 * 64];
    __shared__ float ws[64 * 64];
    const int t = threadIdx.x;
    const int bi = blockIdx.x / 12, bj = blockIdx.x % 12;
    // stage proj weights early (consumed after the post-attn barrier)
    #pragma unroll
    for (int it = 0; it < 4; ++it) {
        int l = it * 256 + t;
        int j = l >> 4, cs = (l & 15) * 4;
        *(float4*)&ws[swz(j, cs, j >> 1)] = *(const float4*)&pw[j * 64 + cs];
    }
    // ---------------- attention ----------------
    const int r = t & 3, g = t >> 2;
    const int h = g & 1, pl = g >> 1;
    const int i = bi * 4 + (pl >> 3), jx = bj * 8 + (pl & 7);
    const int p = i * HW + jx;
    int si = i - 3;  si = si < 0 ? 0 : (si > 89 ? 89 : si);
    int sj = jx - 3; sj = sj < 0 ? 0 : (sj > 89 ? 89 : sj);
    float4 q0, q1;
    {
        const float4* qp = (const float4*)(qkv + p * QN + h * 32 + r * 8);
        q0 = qp[0]; q1 = qp[1];
        q0.x *= SCALE; q0.y *= SCALE; q0.z *= SCALE; q0.w *= SCALE;
        q1.x *= SCALE; q1.y *= SCALE; q1.z *= SCALE; q1.w *= SCALE;
    }
    const float* kb = qkv + (si * HW + sj) * QN + 64 + h * 32 + r * 8;
    float lg[49];
    #pragma unroll
    for (int a = 0; a < 7; ++a) {
        #pragma unroll
        for (int b = 0; b < 7; ++b) {
            const float4* kp = (const float4*)(kb + (a * HW + b) * QN);
            float4 k0 = kp[0], k1 = kp[1];
            float s = q0.x * k0.x;
            s = fmaf(q0.y, k0.y, s); s = fmaf(q0.z, k0.z, s); s = fmaf(q0.w, k0.w, s);
            s = fmaf(q1.x, k1.x, s); s = fmaf(q1.y, k1.y, s);
            s = fmaf(q1.z, k1.z, s); s = fmaf(q1.w, k1.w, s);
            s += __shfl_xor(s, 1);   // quad butterfly: all 4 lanes get full dot
            s += __shfl_xor(s, 2);
            lg[a * 7 + b] = s;
        }
    }
    {
        const float* rp = rpb + h * 169;
        const int rh0 = si - i + 6, rw0 = sj - jx + 6;
        #pragma unroll
        for (int a = 0; a < 7; ++a)
            #pragma unroll
            for (int b = 0; b < 7; ++b)
                lg[a * 7 + b] += rp[(rh0 + a) * 13 + rw0 + b];
    }
    if (HASPREV) {
        const float4* pp = (const float4*)(prev + (p * 2 + h) * ASTRIDE);
        #pragma unroll
        for (int k = 0; k < 12; ++k) {
            float4 z = pp[k];
            lg[k * 4]     += z.x; lg[k * 4 + 1] += z.y;
            lg[k * 4 + 2] += z.z; lg[k * 4 + 3] += z.w;
        }
        lg[48] += ((const float*)pp)[48];
    }
    float mx = lg[0];
    #pragma unroll
    for (int n = 1; n < 49; ++n) mx = fmaxf(mx, lg[n]);
    float sum = 0.f;
    #pragma unroll
    for (int n = 0; n < 49; ++n) { float e = expf(lg[n] - mx); lg[n] = e; sum += e; }
    const float inv = 1.f / sum;
    #pragma unroll
    for (int n = 0; n < 49; ++n) lg[n] *= inv;
    if (!LAST && r == 0) {
        float* cb = cur + (p * 2 + h) * ASTRIDE;
        #pragma unroll
        for (int k = 0; k < 12; ++k)
            *(float4*)&cb[k * 4] = make_float4(lg[k * 4], lg[k * 4 + 1], lg[k * 4 + 2], lg[k * 4 + 3]);
        cb[48] = lg[48];
    }
    float4 a0 = make_float4(0.f, 0.f, 0.f, 0.f), a1 = a0;
    const float* vb = kb + 64;
    #pragma unroll
    for (int a = 0; a < 7; ++a) {
        #pragma unroll
        for (int b = 0; b < 7; ++b) {
            const float4* vp = (const float4*)(vb + (a * HW + b) * QN);
            float4 v0 = vp[0], v1 = vp[1];
            const float w0 = lg[a * 7 + b];
            a0.x = fmaf(w0, v0.x, a0.x); a0.y = fmaf(w0, v0.y, a0.y);
            a0.z = fmaf(w0, v0.z, a0.z); a0.w = fmaf(w0, v0.w, a0.w);
            a1.x = fmaf(w0, v1.x, a1.x); a1.y = fmaf(w0, v1.y, a1.y);
            a1.z = fmaf(w0, v1.z, a1.z); a1.w = fmaf(w0, v1.w, a1.w);
        }
    }
    {
        const int c0 = h * 32 + r * 8;
        *(float4*)&xs[swz(pl, c0, pl >> 2)]     = a0;
        *(float4*)&xs[swz(pl, c0 + 4, pl >> 2)] = a1;
    }
    __syncthreads();
    // ---------------- proj ----------------
    const int pxg = t & 7, jo = t >> 3;     // 4 px x 2 j per thread
    const int j0 = jo * 2;
    float acc[4][2];
    {
        float b0 = pb[j0], b1 = pb[j0 + 1];
        #pragma unroll
        for (int ii = 0; ii < 4; ++ii) { acc[ii][0] = b0; acc[ii][1] = b1; }
    }
    #pragma unroll
    for (int cc = 0; cc < 16; ++cc) {
        float4 xv[4], wv[2];
        #pragma unroll
        for (int ii = 0; ii < 4; ++ii)
            xv[ii] = *(const float4*)&xs[swz(pxg * 4 + ii, cc * 4, pxg)];
        wv[0] = *(const float4*)&ws[swz(j0, cc * 4, jo)];
        wv[1] = *(const float4*)&ws[swz(j0 + 1, cc * 4, jo)];
        #pragma unroll
        for (int ii = 0; ii < 4; ++ii)
            #pragma unroll
            for (int jj = 0; jj < 2; ++jj) {
                acc[ii][jj] = fmaf(xv[ii].x, wv[jj].x, acc[ii][jj]);
                acc[ii][jj] = fmaf(xv[ii].y, wv[jj].y, acc[ii][jj]);
                acc[ii][jj] = fmaf(xv[ii].z, wv[jj].z, acc[ii][jj]);
                acc[ii][jj] = fmaf(xv[ii].w, wv[jj].w, acc[ii][jj]);
            }
    }
    if (!LAST) {
        #pragma unroll
        for (int ii = 0; ii < 4; ++ii) {
            int pg = pmap(bi, bj, pxg * 4 + ii);
            *(float2*)&xh[pg * 64 + j0] = make_float2(acc[ii][0], acc[ii][1]);
        }
    } else {
        __syncthreads();   // everyone done reading attn data in xs
        #pragma unroll
        for (int ii = 0; ii < 4; ++ii) {
            int px = pxg * 4 + ii;
            *(float2*)&xs[swz(px, j0, pxg)] = make_float2(acc[ii][0], acc[ii][1]);
        }
        __syncthreads();
        #pragma unroll
        for (int it = 0; it < 8; ++it) {
            int px = it * 4 + (t >> 6), c = t & 63;
            outp[c * NPIX + pmap(bi, bj, px)] = xs[swz(px, c, px >> 2)];
        }
    }
}

extern "C" void kernel_launch(void* const* d_in, const int* in_sizes, int n_in,
                              void* d_out, int out_size, void* d_ws, size_t ws_size,
                              hipStream_t stream)
{
    const float* x   = (const float*)d_in[0];
    const float* qw  = (const float*)d_in[1];   // (3,192,64)
    const float* qb  = (const float*)d_in[2];   // (3,192)
    const float* pw  = (const float*)d_in[3];   // (3,64,64)
    const float* pb  = (const float*)d_in[4];   // (3,64)
    const float* rpb = (const float*)d_in[5];   // (3,2,13,13)
    float* out = (float*)d_out;
    float* ws  = (float*)d_ws;

    float* qkv  = ws;                    // 1,769,472 floats
    float* attA = qkv + 1769472;         //   958,464 (18432 * 52)
    float* attB = attA + 958464;         //   958,464
    float* xh   = attB + 958464;         //   589,824
    // total 17.1 MB

    k_qkv<0><<<288, 256, 0, stream>>>(x, qw, qb, qkv);
    k_stage<0, 0><<<288, 256, 0, stream>>>(qkv, rpb,       nullptr, attA, pw,        pb,       xh, nullptr);
    k_qkv<1><<<288, 256, 0, stream>>>(xh, qw + 12288, qb + 192, qkv);
    k_stage<1, 0><<<288, 256, 0, stream>>>(qkv, rpb + 338, attA,    attB, pw + 4096, pb + 64,  xh, nullptr);
    k_qkv<1><<<288, 256, 0, stream>>>(xh, qw + 24576, qb + 384, qkv);
    k_stage<1, 1><<<288, 256, 0, stream>>>(qkv, rpb + 676, attB, nullptr, pw + 8192, pb + 128, nullptr, out);
}

// Round 3
// 150.808 us; speedup vs baseline: 1.9759x; 1.2469x over previous
//
#include <hip/hip_runtime.h>

#define HW 96
#define NPIX 9216
#define QN 192
#define ASTRIDE 52
#define SCALE 0.17677669529663687f
#define NT 576          // threads per block (9 waves)
#define TP 36           // 6x6 pixel tile

// XOR-swizzled LDS word addresses (linear rows of 64 words).
__device__ __forceinline__ int xswz(int row, int col) {
    return row * 64 + (((col & 60) ^ (((row >> 2) & 7) << 2)) | (col & 3));
}
__device__ __forceinline__ int wswz(int row, int col) {
    return row * 64 + (((col & 60) ^ ((row & 7) << 2)) | (col & 3));
}

// 36px x 192j x 64c GEMM from LDS tiles. xs[36][64] (xswz), ws[192][64] (wswz).
// 576 threads: pxg = t%9 owns 4 px, jo = t/9 owns 3 consecutive j.
__device__ __forceinline__ void qkv_gemm(const float* __restrict__ xs,
                                         const float* __restrict__ ws,
                                         const float* __restrict__ qb,
                                         float* __restrict__ qkv,
                                         int i0, int j0c, int t)
{
    const int pxg = t % 9;
    const int jo  = t / 9;
    const int jb  = jo * 3;
    float acc[4][3];
    #pragma unroll
    for (int jj = 0; jj < 3; ++jj) {
        float bv = qb[jb + jj];
        #pragma unroll
        for (int ii = 0; ii < 4; ++ii) acc[ii][jj] = bv;
    }
    #pragma unroll
    for (int cc = 0; cc < 16; ++cc) {
        float4 xv[4], wv[3];
        #pragma unroll
        for (int ii = 0; ii < 4; ++ii)
            xv[ii] = *(const float4*)&xs[xswz(pxg * 4 + ii, cc * 4)];
        #pragma unroll
        for (int jj = 0; jj < 3; ++jj)
            wv[jj] = *(const float4*)&ws[wswz(jb + jj, cc * 4)];
        #pragma unroll
        for (int ii = 0; ii < 4; ++ii)
            #pragma unroll
            for (int jj = 0; jj < 3; ++jj) {
                acc[ii][jj] = fmaf(xv[ii].x, wv[jj].x, acc[ii][jj]);
                acc[ii][jj] = fmaf(xv[ii].y, wv[jj].y, acc[ii][jj]);
                acc[ii][jj] = fmaf(xv[ii].z, wv[jj].z, acc[ii][jj]);
                acc[ii][jj] = fmaf(xv[ii].w, wv[jj].w, acc[ii][jj]);
            }
    }
    #pragma unroll
    for (int ii = 0; ii < 4; ++ii) {
        int px = pxg * 4 + ii;
        float* o = qkv + ((i0 + px / 6) * HW + j0c + px % 6) * QN + jb;
        o[0] = acc[ii][0]; o[1] = acc[ii][1]; o[2] = acc[ii][2];
    }
}

__global__ __launch_bounds__(NT) void k_qkv0(const float* __restrict__ x,
                                             const float* __restrict__ qw,
                                             const float* __restrict__ qb,
                                             float* __restrict__ qkv)
{
    __shared__ float xs[TP * 64];
    __shared__ float ws[QN * 64];
    const int t = threadIdx.x;
    const int i0 = (blockIdx.x >> 4) * 6, j0c = (blockIdx.x & 15) * 6;
    #pragma unroll
    for (int it = 0; it < 4; ++it) {
        int l = it * NT + t;
        int px = l % 36, c = l / 36;
        xs[xswz(px, c)] = x[c * NPIX + (i0 + px / 6) * HW + j0c + px % 6];
    }
    #pragma unroll
    for (int it = 0; it < 6; ++it) {
        int l = it * NT + t;
        if (l < 3072) {
            int j = l >> 4, cs = (l & 15) << 2;
            *(float4*)&ws[wswz(j, cs)] = *(const float4*)&qw[j * 64 + cs];
        }
    }
    __syncthreads();
    qkv_gemm(xs, ws, qb, qkv, i0, j0c, t);
}

// Fused: neighborhood attention + proj + (next-stage qkv | final output).
// Attention: 72 groups of 8 lanes; lane owns 4 of 32 dims.
template <int HASPREV, int LAST>
__global__ __launch_bounds__(NT) void k_stage(const float* __restrict__ qkv,
                                              const float* __restrict__ rpb,
                                              const float* __restrict__ prev,
                                              float* __restrict__ cur,
                                              const float* __restrict__ pw,
                                              const float* __restrict__ pb,
                                              const float* __restrict__ qw,
                                              const float* __restrict__ qb,
                                              float* __restrict__ qkvn,
                                              float* __restrict__ outp)
{
    __shared__ float xs[TP * 64];
    __shared__ float ws[QN * 64];
    __shared__ float rpb_s[338];
    const int t = threadIdx.x;
    const int i0 = (blockIdx.x >> 4) * 6, j0c = (blockIdx.x & 15) * 6;
    // stage proj weights + bias table (consumed after barrier 1)
    #pragma unroll
    for (int it = 0; it < 2; ++it) {
        int l = it * NT + t;
        if (l < 1024) {
            int j = l >> 4, cs = (l & 15) << 2;
            *(float4*)&ws[wswz(j, cs)] = *(const float4*)&pw[j * 64 + cs];
        }
    }
    if (t < 338) rpb_s[t] = rpb[t];
    // ---------------- attention ----------------
    const int r = t & 7, g = t >> 3;
    const int h = g & 1, pl = g >> 1;
    const int i = i0 + pl / 6, jx = j0c + pl % 6;
    const int p = i * HW + jx;
    int si = i - 3;  si = si < 0 ? 0 : (si > 89 ? 89 : si);
    int sj = jx - 3; sj = sj < 0 ? 0 : (sj > 89 ? 89 : sj);
    float4 q0;
    {
        q0 = *(const float4*)(qkv + p * QN + h * 32 + r * 4);
        q0.x *= SCALE; q0.y *= SCALE; q0.z *= SCALE; q0.w *= SCALE;
    }
    const float* kb = qkv + (si * HW + sj) * QN + 64 + h * 32 + r * 4;
    float lg[49];
    #pragma unroll
    for (int a = 0; a < 7; ++a) {
        #pragma unroll
        for (int b = 0; b < 7; ++b) {
            float4 k0 = *(const float4*)(kb + (a * HW + b) * QN);
            float s = q0.x * k0.x;
            s = fmaf(q0.y, k0.y, s); s = fmaf(q0.z, k0.z, s); s = fmaf(q0.w, k0.w, s);
            s += __shfl_xor(s, 1);
            s += __shfl_xor(s, 2);
            s += __shfl_xor(s, 4);
            lg[a * 7 + b] = s;
        }
    }
    __syncthreads();                          // rpb_s / ws staged
    {
        const float* rp = rpb_s + h * 169;
        const int rh0 = si - i + 6, rw0 = sj - jx + 6;
        #pragma unroll
        for (int a = 0; a < 7; ++a)
            #pragma unroll
            for (int b = 0; b < 7; ++b)
                lg[a * 7 + b] += rp[(rh0 + a) * 13 + rw0 + b];
    }
    if (HASPREV) {
        const float4* pp = (const float4*)(prev + (p * 2 + h) * ASTRIDE);
        #pragma unroll
        for (int k = 0; k < 12; ++k) {
            float4 z = pp[k];
            lg[k * 4]     += z.x; lg[k * 4 + 1] += z.y;
            lg[k * 4 + 2] += z.z; lg[k * 4 + 3] += z.w;
        }
        lg[48] += ((const float*)pp)[48];
    }
    float mx = lg[0];
    #pragma unroll
    for (int n = 1; n < 49; ++n) mx = fmaxf(mx, lg[n]);
    float sum = 0.f;
    #pragma unroll
    for (int n = 0; n < 49; ++n) { float e = expf(lg[n] - mx); lg[n] = e; sum += e; }
    const float inv = 1.f / sum;
    #pragma unroll
    for (int n = 0; n < 49; ++n) lg[n] *= inv;
    if (!LAST && r == 0) {
        float* cb = cur + (p * 2 + h) * ASTRIDE;
        #pragma unroll
        for (int k = 0; k < 12; ++k)
            *(float4*)&cb[k * 4] = make_float4(lg[k * 4], lg[k * 4 + 1], lg[k * 4 + 2], lg[k * 4 + 3]);
        cb[48] = lg[48];
    }
    {
        float4 a0 = make_float4(0.f, 0.f, 0.f, 0.f);
        const float* vb = kb + 64;
        #pragma unroll
        for (int a = 0; a < 7; ++a) {
            #pragma unroll
            for (int b = 0; b < 7; ++b) {
                float4 v0 = *(const float4*)(vb + (a * HW + b) * QN);
                const float w0 = lg[a * 7 + b];
                a0.x = fmaf(w0, v0.x, a0.x); a0.y = fmaf(w0, v0.y, a0.y);
                a0.z = fmaf(w0, v0.z, a0.z); a0.w = fmaf(w0, v0.w, a0.w);
            }
        }
        *(float4*)&xs[xswz(pl, h * 32 + r * 4)] = a0;
    }
    __syncthreads();                          // attn tile in xs
    // ---------------- proj ----------------
    const int pxg = t % 18, jo = t / 18;      // 2 px x 2 j
    const int jb = jo * 2;
    float pacc[2][2];
    {
        float b0 = pb[jb], b1 = pb[jb + 1];
        pacc[0][0] = b0; pacc[1][0] = b0; pacc[0][1] = b1; pacc[1][1] = b1;
    }
    #pragma unroll
    for (int cc = 0; cc < 16; ++cc) {
        float4 xv[2], wv[2];
        #pragma unroll
        for (int ii = 0; ii < 2; ++ii)
            xv[ii] = *(const float4*)&xs[xswz(pxg * 2 + ii, cc * 4)];
        #pragma unroll
        for (int jj = 0; jj < 2; ++jj)
            wv[jj] = *(const float4*)&ws[wswz(jb + jj, cc * 4)];
        #pragma unroll
        for (int ii = 0; ii < 2; ++ii)
            #pragma unroll
            for (int jj = 0; jj < 2; ++jj) {
                pacc[ii][jj] = fmaf(xv[ii].x, wv[jj].x, pacc[ii][jj]);
                pacc[ii][jj] = fmaf(xv[ii].y, wv[jj].y, pacc[ii][jj]);
                pacc[ii][jj] = fmaf(xv[ii].z, wv[jj].z, pacc[ii][jj]);
                pacc[ii][jj] = fmaf(xv[ii].w, wv[jj].w, pacc[ii][jj]);
            }
    }
    __syncthreads();                          // done reading xs/ws
    #pragma unroll
    for (int ii = 0; ii < 2; ++ii)
        #pragma unroll
        for (int jj = 0; jj < 2; ++jj)
            xs[xswz(pxg * 2 + ii, jb + jj)] = pacc[ii][jj];
    if (!LAST) {
        #pragma unroll
        for (int it = 0; it < 6; ++it) {
            int l = it * NT + t;
            if (l < 3072) {
                int j = l >> 4, cs = (l & 15) << 2;
                *(float4*)&ws[wswz(j, cs)] = *(const float4*)&qw[j * 64 + cs];
            }
        }
    }
    __syncthreads();                          // xh in xs, next weights in ws
    if (LAST) {
        #pragma unroll
        for (int it = 0; it < 4; ++it) {
            int l = it * NT + t;
            int px = l % 36, c = l / 36;
            outp[c * NPIX + (i0 + px / 6) * HW + j0c + px % 6] = xs[xswz(px, c)];
        }
        return;
    }
    qkv_gemm(xs, ws, qb, qkvn, i0, j0c, t);
}

extern "C" void kernel_launch(void* const* d_in, const int* in_sizes, int n_in,
                              void* d_out, int out_size, void* d_ws, size_t ws_size,
                              hipStream_t stream)
{
    const float* x   = (const float*)d_in[0];
    const float* qw  = (const float*)d_in[1];   // (3,192,64)
    const float* qb  = (const float*)d_in[2];   // (3,192)
    const float* pw  = (const float*)d_in[3];   // (3,64,64)
    const float* pb  = (const float*)d_in[4];   // (3,64)
    const float* rpb = (const float*)d_in[5];   // (3,2,13,13)
    float* out = (float*)d_out;
    float* ws  = (float*)d_ws;

    float* qkvA = ws;                    // 1,769,472 floats
    float* qkvB = qkvA + 1769472;        // 1,769,472
    float* attA = qkvB + 1769472;        //   958,464
    float* attB = attA + 958464;         //   958,464  (total ~21.8 MB)

    k_qkv0<<<256, NT, 0, stream>>>(x, qw, qb, qkvA);
    k_stage<0, 0><<<256, NT, 0, stream>>>(qkvA, rpb,       nullptr, attA,
                                          pw,        pb,       qw + 12288, qb + 192, qkvB, nullptr);
    k_stage<1, 0><<<256, NT, 0, stream>>>(qkvB, rpb + 338, attA,    attB,
                                          pw + 4096, pb + 64,  qw + 24576, qb + 384, qkvA, nullptr);
    k_stage<1, 1><<<256, NT, 0, stream>>>(qkvA, rpb + 676, attB,    nullptr,
                                          pw + 8192, pb + 128, nullptr,    nullptr,  nullptr, out);
}